// Round 2
// baseline (1111.074 us; speedup 1.0000x reference)
//
#include <hip/hip_runtime.h>
#include <stdint.h>

// Problem constants (B=8, S=1024, D=256, K=16384)
#define N_ROWS 8192
#define D_DIM  256
#define K_CENT 16384

typedef __attribute__((ext_vector_type(8))) short bf16x8;
typedef __attribute__((ext_vector_type(4))) float f32x4;
typedef __attribute__((ext_vector_type(8))) unsigned short u16x8;

// Monotone order-preserving float->uint mapping
__device__ __forceinline__ uint32_t fkey(float f) {
    uint32_t b = __float_as_uint(f);
    return (b & 0x80000000u) ? ~b : (b | 0x80000000u);
}

// f32 -> bf16 round-to-nearest-even (no NaN in data)
__device__ __forceinline__ unsigned short f2bf(float f) {
    uint32_t u = __float_as_uint(f);
    uint32_t r = u + 0x7FFFu + ((u >> 16) & 1u);
    return (unsigned short)(r >> 16);
}

__device__ __forceinline__ void gload_lds16(const void* g, void* l) {
    __builtin_amdgcn_global_load_lds(
        (const __attribute__((address_space(1))) void*)g,
        (__attribute__((address_space(3))) void*)l, 16, 0, 0);
}

// ---------------- shared: norms (one wave per row) ----------------
__global__ void norms_kernel(const float* __restrict__ feat,
                             const float* __restrict__ cent,
                             float* __restrict__ xnorm,
                             float* __restrict__ cnorm) {
    int gtid = blockIdx.x * blockDim.x + threadIdx.x;
    int wave = gtid >> 6;
    int lane = gtid & 63;
    if (wave >= N_ROWS + K_CENT) return;
    const float* src = (wave < N_ROWS) ? (feat + (size_t)wave * D_DIM)
                                       : (cent + (size_t)(wave - N_ROWS) * D_DIM);
    float4 v = ((const float4*)src)[lane];
    float s = v.x * v.x + v.y * v.y + v.z * v.z + v.w * v.w;
    #pragma unroll
    for (int off = 32; off >= 1; off >>= 1) s += __shfl_xor(s, off);
    if (lane == 0) {
        if (wave < N_ROWS) xnorm[wave] = s;
        else cnorm[wave - N_ROWS] = s;
    }
}

// ---------------- fast path: bf16 conversion ----------------
__global__ void convert_bf16(const float* __restrict__ feat,
                             const float* __restrict__ cent,
                             unsigned short* __restrict__ Abf,
                             unsigned short* __restrict__ Bbf) {
    size_t i = ((size_t)blockIdx.x * blockDim.x + threadIdx.x) * 8;
    const size_t NA = (size_t)N_ROWS * D_DIM;          // 2097152
    const size_t NT = NA + (size_t)K_CENT * D_DIM;     // 6291456
    if (i >= NT) return;
    const float* src;
    unsigned short* dst;
    if (i < NA) { src = feat + i; dst = Abf + i; }
    else        { src = cent + (i - NA); dst = Bbf + (i - NA); }
    float4 v0 = ((const float4*)src)[0];
    float4 v1 = ((const float4*)src)[1];
    u16x8 o;
    o[0] = f2bf(v0.x); o[1] = f2bf(v0.y); o[2] = f2bf(v0.z); o[3] = f2bf(v0.w);
    o[4] = f2bf(v1.x); o[5] = f2bf(v1.y); o[6] = f2bf(v1.z); o[7] = f2bf(v1.w);
    *(u16x8*)dst = o;
}

// ---------------- fast path: MFMA dist GEMM ----------------
#define GBM 128
#define GBN 128
#define GBK 32

__global__ __launch_bounds__(256, 2)
void dist_mfma(const unsigned short* __restrict__ Abf,   // 8192 x 256 bf16
               const unsigned short* __restrict__ Bbf,   // 16384 x 256 bf16
               const float* __restrict__ xnorm,
               const float* __restrict__ cnorm,
               float* __restrict__ dist,                 // 8192 x 16384
               float* __restrict__ blockmins) {          // 8192 x 256 (64-col blocks)
    __shared__ unsigned short As[GBM][GBK];   // 8KB
    __shared__ unsigned short Bs[GBN][GBK];   // 8KB

    const int tid = threadIdx.x;
    const int lane = tid & 63;
    const int w = tid >> 6;
    const int wr = w >> 1, wc = w & 1;         // wave -> 64x64 subtile
    const int row0 = blockIdx.x * GBM;
    const int col0 = blockIdx.y * GBN;
    const int cl = lane & 15, kg = lane >> 4;

    f32x4 zero = {0.f, 0.f, 0.f, 0.f};
    f32x4 acc[4][4];
    #pragma unroll
    for (int m = 0; m < 4; ++m)
        #pragma unroll
        for (int n = 0; n < 4; ++n) acc[m][n] = zero;

    for (int kt = 0; kt < D_DIM / GBK; ++kt) {
        // stage A: 128 rows x 32 k = 512 x 16B chunks, 2 per thread
        #pragma unroll
        for (int j = 0; j < 2; ++j) {
            int f = tid + 256 * j;
            int r = f >> 2, kq = f & 3;
            gload_lds16(Abf + (size_t)(row0 + r) * D_DIM + kt * GBK + kq * 8,
                        &As[0][0] + f * 8);
        }
        // stage B
        #pragma unroll
        for (int j = 0; j < 2; ++j) {
            int f = tid + 256 * j;
            int r = f >> 2, kq = f & 3;
            gload_lds16(Bbf + (size_t)(col0 + r) * D_DIM + kt * GBK + kq * 8,
                        &Bs[0][0] + f * 8);
        }
        __syncthreads();

        bf16x8 af[4], bfr[4];
        #pragma unroll
        for (int m = 0; m < 4; ++m)
            af[m] = *(const bf16x8*)&As[wr * 64 + m * 16 + cl][kg * 8];
        #pragma unroll
        for (int n = 0; n < 4; ++n)
            bfr[n] = *(const bf16x8*)&Bs[wc * 64 + n * 16 + cl][kg * 8];

        #pragma unroll
        for (int m = 0; m < 4; ++m)
            #pragma unroll
            for (int n = 0; n < 4; ++n)
                acc[m][n] = __builtin_amdgcn_mfma_f32_16x16x32_bf16(
                    af[m], bfr[n], acc[m][n], 0, 0, 0);
        __syncthreads();
    }

    // epilogue: dist = (xnorm - 2*dot) + cnorm; per-(row,64col) min
    float cn[4];
    #pragma unroll
    for (int n = 0; n < 4; ++n) cn[n] = cnorm[col0 + wc * 64 + n * 16 + cl];
    const int bcol = blockIdx.y * 2 + wc;

    #pragma unroll
    for (int m = 0; m < 4; ++m) {
        const int rbase = row0 + wr * 64 + m * 16 + kg * 4;
        float4 xn4 = *(const float4*)&xnorm[rbase];
        float xn[4] = {xn4.x, xn4.y, xn4.z, xn4.w};
        float rmin[4] = {3.4e38f, 3.4e38f, 3.4e38f, 3.4e38f};
        #pragma unroll
        for (int n = 0; n < 4; ++n) {
            const int col = col0 + wc * 64 + n * 16 + cl;
            f32x4 a = acc[m][n];
            #pragma unroll
            for (int i = 0; i < 4; ++i) {
                float d = (xn[i] - 2.f * a[i]) + cn[n];
                dist[(size_t)(rbase + i) * K_CENT + col] = d;
                rmin[i] = fminf(rmin[i], d);
            }
        }
        #pragma unroll
        for (int i = 0; i < 4; ++i) {
            #pragma unroll
            for (int off = 8; off >= 1; off >>= 1)
                rmin[i] = fminf(rmin[i], __shfl_xor(rmin[i], off));
        }
        if (cl == 0) {
            #pragma unroll
            for (int i = 0; i < 4; ++i)
                blockmins[(size_t)(rbase + i) * 256 + bcol] = rmin[i];
        }
    }
}

// ---------------- fast path: exact argmin recheck + finalize ----------------
// One wave per row; 4 rows per 256-thread block.
__global__ __launch_bounds__(256)
void recheck_finalize(const float* __restrict__ feat,
                      const float* __restrict__ cent,
                      const float* __restrict__ xnorm,
                      const float* __restrict__ cnorm,
                      const float* __restrict__ blockmins,
                      float* __restrict__ quant,
                      float* __restrict__ ids) {
    __shared__ float xsh[4][256];
    __shared__ float bms[4][256];
    const int tid = threadIdx.x;
    const int wv = tid >> 6;
    const int lane = tid & 63;
    const int row = blockIdx.x * 4 + wv;

    // load feature row + blockmins row into LDS (per-wave, float4/lane)
    ((float4*)&xsh[wv][0])[lane] = ((const float4*)(feat + (size_t)row * D_DIM))[lane];
    ((float4*)&bms[wv][0])[lane] = ((const float4*)(blockmins + (size_t)row * 256))[lane];

    // global approx min over the 256 block mins
    float4 bm4 = ((float4*)&bms[wv][0])[lane];
    float gmin = fminf(fminf(bm4.x, bm4.y), fminf(bm4.z, bm4.w));
    #pragma unroll
    for (int off = 32; off >= 1; off >>= 1)
        gmin = fminf(gmin, __shfl_xor(gmin, off));

    const float thr = gmin + 2.0f;   // covers worst-case bf16 dot error (~<1.0)
    const float xn = xnorm[row];

    unsigned long long best = 0xFFFFFFFFFFFFFFFFull;
    for (int b = 0; b < 256; ++b) {
        if (bms[wv][b] <= thr) {    // wave-uniform branch
            const int c = b * 64 + lane;
            const float4* crow = (const float4*)(cent + (size_t)c * D_DIM);
            float a0 = 0.f, a1 = 0.f, a2 = 0.f, a3 = 0.f;
            #pragma unroll 8
            for (int k4 = 0; k4 < 64; ++k4) {
                float4 cv = crow[k4];
                float4 xv = *(const float4*)&xsh[wv][k4 * 4];
                a0 = fmaf(xv.x, cv.x, a0);
                a1 = fmaf(xv.y, cv.y, a1);
                a2 = fmaf(xv.z, cv.z, a2);
                a3 = fmaf(xv.w, cv.w, a3);
            }
            float dot = (a0 + a1) + (a2 + a3);
            float dd = (xn - 2.f * dot) + cnorm[c];
            unsigned long long key =
                ((unsigned long long)fkey(dd) << 32) | (unsigned)c;
            best = (key < best) ? key : best;
        }
    }
    #pragma unroll
    for (int off = 32; off >= 1; off >>= 1) {
        unsigned long long o = __shfl_xor(best, off);
        best = (o < best) ? o : best;
    }

    const unsigned bidx = (unsigned)(best & 0xFFFFFFFFu);
    if (lane == 0) ids[row] = (float)bidx;
    float4 v = ((const float4*)(cent + (size_t)bidx * D_DIM))[lane];
    ((float4*)(quant + (size_t)row * D_DIM))[lane] = v;
}

// ================= fallback path (round-1 exact f32 kernel) =================
__global__ void init_keys(unsigned long long* __restrict__ keys) {
    int i = blockIdx.x * blockDim.x + threadIdx.x;
    if (i < N_ROWS) keys[i] = 0xFFFFFFFFFFFFFFFFull;
}

#define BM 128
#define BN 64
#define BK 32

__global__ __launch_bounds__(256, 2)
void dist_gemm(const float* __restrict__ A, const float* __restrict__ B,
               const float* __restrict__ xnorm, const float* __restrict__ cnorm,
               float* __restrict__ dist, unsigned long long* __restrict__ rowkeys) {
    __shared__ float As[BK][BM + 4];
    __shared__ float Bs[BK][BN + 4];
    const int tid = threadIdx.x;
    const int tx = tid & 15;
    const int ty = tid >> 4;
    const int row0 = blockIdx.x * BM;
    const int col0 = blockIdx.y * BN;
    float acc[8][4];
    #pragma unroll
    for (int i = 0; i < 8; ++i)
        #pragma unroll
        for (int j = 0; j < 4; ++j) acc[i][j] = 0.f;
    const float4* A4 = (const float4*)A;
    const float4* B4 = (const float4*)B;
    for (int kt = 0; kt < D_DIM / BK; ++kt) {
        #pragma unroll
        for (int j = 0; j < 4; ++j) {
            int f = tid + 256 * j;
            int r = f >> 3, kq = f & 7;
            float4 a = A4[(size_t)(row0 + r) * 64 + kt * 8 + kq];
            As[kq * 4 + 0][r] = a.x; As[kq * 4 + 1][r] = a.y;
            As[kq * 4 + 2][r] = a.z; As[kq * 4 + 3][r] = a.w;
        }
        #pragma unroll
        for (int j = 0; j < 2; ++j) {
            int f = tid + 256 * j;
            int r = f >> 3, kq = f & 7;
            float4 b = B4[(size_t)(col0 + r) * 64 + kt * 8 + kq];
            Bs[kq * 4 + 0][r] = b.x; Bs[kq * 4 + 1][r] = b.y;
            Bs[kq * 4 + 2][r] = b.z; Bs[kq * 4 + 3][r] = b.w;
        }
        __syncthreads();
        #pragma unroll
        for (int kk = 0; kk < BK; ++kk) {
            float4 a0 = *(const float4*)&As[kk][8 * ty];
            float4 a1 = *(const float4*)&As[kk][8 * ty + 4];
            float4 b  = *(const float4*)&Bs[kk][4 * tx];
            float av[8] = {a0.x, a0.y, a0.z, a0.w, a1.x, a1.y, a1.z, a1.w};
            float bv[4] = {b.x, b.y, b.z, b.w};
            #pragma unroll
            for (int i = 0; i < 8; ++i)
                #pragma unroll
                for (int j = 0; j < 4; ++j)
                    acc[i][j] = fmaf(av[i], bv[j], acc[i][j]);
        }
        __syncthreads();
    }
    float cn[4];
    #pragma unroll
    for (int j = 0; j < 4; ++j) cn[j] = cnorm[col0 + 4 * tx + j];
    #pragma unroll
    for (int i = 0; i < 8; ++i) {
        int row = row0 + 8 * ty + i;
        float xn = xnorm[row];
        float4 dv;
        dv.x = (xn - 2.f * acc[i][0]) + cn[0];
        dv.y = (xn - 2.f * acc[i][1]) + cn[1];
        dv.z = (xn - 2.f * acc[i][2]) + cn[2];
        dv.w = (xn - 2.f * acc[i][3]) + cn[3];
        ((float4*)(dist + (size_t)row * K_CENT + col0 + 4 * tx))[0] = dv;
        int cbase = col0 + 4 * tx;
        float mv = dv.x; int mi = cbase;
        if (dv.y < mv) { mv = dv.y; mi = cbase + 1; }
        if (dv.z < mv) { mv = dv.z; mi = cbase + 2; }
        if (dv.w < mv) { mv = dv.w; mi = cbase + 3; }
        #pragma unroll
        for (int off = 8; off >= 1; off >>= 1) {
            float ov = __shfl_down(mv, off);
            int   oi = __shfl_down(mi, off);
            if (ov < mv || (ov == mv && oi < mi)) { mv = ov; mi = oi; }
        }
        if (tx == 0) {
            unsigned long long key =
                ((unsigned long long)fkey(mv) << 32) | (unsigned)mi;
            atomicMin(&rowkeys[row], key);
        }
    }
}

__global__ void finalize_kernel(const unsigned long long* __restrict__ rowkeys,
                                const float* __restrict__ cent,
                                float* __restrict__ quant,
                                float* __restrict__ ids) {
    int row = blockIdx.x;
    int lane = threadIdx.x;
    unsigned idx = (unsigned)(rowkeys[row] & 0xFFFFFFFFu);
    if (lane == 0) ids[row] = (float)idx;
    float4 v = ((const float4*)(cent + (size_t)idx * D_DIM))[lane];
    ((float4*)(quant + (size_t)row * D_DIM))[lane] = v;
}

// ============================ launch ============================
extern "C" void kernel_launch(void* const* d_in, const int* in_sizes, int n_in,
                              void* d_out, int out_size, void* d_ws, size_t ws_size,
                              hipStream_t stream) {
    const float* feat = (const float*)d_in[0];   // 8192 x 256
    const float* cent = (const float*)d_in[1];   // 16384 x 256

    float* out = (float*)d_out;
    float* quant = out;                 // 2097152
    float* ids   = out + 2097152;       // 8192
    float* dist  = out + 2105344;       // 8192*16384

    const size_t REQUIRED = (size_t)22 * 1024 * 1024;
    if (ws_size >= REQUIRED) {
        // fast path: bf16 MFMA + exact recheck
        char* ws = (char*)d_ws;
        unsigned short* Abf = (unsigned short*)ws;                       // 4MB
        unsigned short* Bbf = (unsigned short*)(ws + (4u << 20));        // 8MB
        float* blockmins    = (float*)(ws + (12u << 20));                // 8MB
        float* xnorm        = (float*)(ws + (20u << 20));                // 32KB
        float* cnorm        = xnorm + N_ROWS;                            // 64KB

        convert_bf16<<<3072, 256, 0, stream>>>(feat, cent, Abf, Bbf);
        {
            int waves = N_ROWS + K_CENT;
            int blocks = (waves * 64 + 255) / 256;
            norms_kernel<<<blocks, 256, 0, stream>>>(feat, cent, xnorm, cnorm);
        }
        dist_mfma<<<dim3(N_ROWS / GBM, K_CENT / GBN), 256, 0, stream>>>(
            Abf, Bbf, xnorm, cnorm, dist, blockmins);
        recheck_finalize<<<N_ROWS / 4, 256, 0, stream>>>(
            feat, cent, xnorm, cnorm, blockmins, quant, ids);
    } else {
        // fallback: round-1 exact f32 path
        float* xnorm = (float*)d_ws;
        float* cnorm = xnorm + N_ROWS;
        unsigned long long* rowkeys =
            (unsigned long long*)((char*)d_ws + (N_ROWS + K_CENT) * sizeof(float));
        init_keys<<<(N_ROWS + 255) / 256, 256, 0, stream>>>(rowkeys);
        {
            int waves = N_ROWS + K_CENT;
            int blocks = (waves * 64 + 255) / 256;
            norms_kernel<<<blocks, 256, 0, stream>>>(feat, cent, xnorm, cnorm);
        }
        dist_gemm<<<dim3(N_ROWS / BM, K_CENT / BN), 256, 0, stream>>>(
            feat, cent, xnorm, cnorm, dist, rowkeys);
        finalize_kernel<<<N_ROWS, 64, 0, stream>>>(rowkeys, cent, quant, ids);
    }
}

// Round 3
// 213.064 us; speedup vs baseline: 5.2147x; 5.2147x over previous
//
#include <hip/hip_runtime.h>
#include <stdint.h>

// Problem constants (B=8, S=1024, D=256, K=16384)
#define N_ROWS 8192
#define D_DIM  256
#define K_CENT 16384

typedef __attribute__((ext_vector_type(8))) short bf16x8;
typedef __attribute__((ext_vector_type(4))) float f32x4;

// Monotone order-preserving float->uint mapping (all dists finite)
__device__ __forceinline__ uint32_t fkey(float f) {
    uint32_t b = __float_as_uint(f);
    return (b & 0x80000000u) ? ~b : (b | 0x80000000u);
}

// f32 -> bf16 round-to-nearest-even
__device__ __forceinline__ unsigned short f2bf(float f) {
    uint32_t u = __float_as_uint(f);
    uint32_t r = u + 0x7FFFu + ((u >> 16) & 1u);
    return (unsigned short)(r >> 16);
}

__device__ __forceinline__ void gload_lds16(const void* g, void* l) {
    __builtin_amdgcn_global_load_lds(
        (const __attribute__((address_space(1))) void*)g,
        (__attribute__((address_space(3))) void*)l, 16, 0, 0);
}

// ---------------- prep: fused bf16 convert + norms (one wave per row) -------
__global__ __launch_bounds__(256)
void prep_kernel(const float* __restrict__ feat,
                 const float* __restrict__ cent,
                 unsigned short* __restrict__ Abf,
                 unsigned short* __restrict__ Bbf,
                 float* __restrict__ xnorm,
                 float* __restrict__ cnorm) {
    int gtid = blockIdx.x * blockDim.x + threadIdx.x;
    int wave = gtid >> 6;
    int lane = gtid & 63;
    if (wave >= N_ROWS + K_CENT) return;
    const float* src;
    unsigned short* dst;
    float* ndst;
    if (wave < N_ROWS) {
        src = feat + (size_t)wave * D_DIM;
        dst = Abf + (size_t)wave * D_DIM;
        ndst = xnorm + wave;
    } else {
        int r = wave - N_ROWS;
        src = cent + (size_t)r * D_DIM;
        dst = Bbf + (size_t)r * D_DIM;
        ndst = cnorm + r;
    }
    float4 v = ((const float4*)src)[lane];
    // same arithmetic order as rounds 1-2 (passed)
    float s = v.x * v.x + v.y * v.y + v.z * v.z + v.w * v.w;
    ushort4 o;
    o.x = f2bf(v.x); o.y = f2bf(v.y); o.z = f2bf(v.z); o.w = f2bf(v.w);
    *(ushort4*)(dst + lane * 4) = o;
    #pragma unroll
    for (int off = 32; off >= 1; off >>= 1) s += __shfl_xor(s, off);
    if (lane == 0) *ndst = s;
}

// ---------------- MFMA dist GEMM (unchanged from round 2) ----------------
#define GBM 128
#define GBN 128
#define GBK 32

__global__ __launch_bounds__(256, 2)
void dist_mfma(const unsigned short* __restrict__ Abf,   // 8192 x 256 bf16
               const unsigned short* __restrict__ Bbf,   // 16384 x 256 bf16
               const float* __restrict__ xnorm,
               const float* __restrict__ cnorm,
               float* __restrict__ dist,                 // 8192 x 16384
               float* __restrict__ blockmins) {          // 8192 x 256 (64-col blocks)
    __shared__ unsigned short As[GBM][GBK];   // 8KB
    __shared__ unsigned short Bs[GBN][GBK];   // 8KB

    const int tid = threadIdx.x;
    const int lane = tid & 63;
    const int w = tid >> 6;
    const int wr = w >> 1, wc = w & 1;         // wave -> 64x64 subtile
    const int row0 = blockIdx.x * GBM;
    const int col0 = blockIdx.y * GBN;
    const int cl = lane & 15, kg = lane >> 4;

    f32x4 zero = {0.f, 0.f, 0.f, 0.f};
    f32x4 acc[4][4];
    #pragma unroll
    for (int m = 0; m < 4; ++m)
        #pragma unroll
        for (int n = 0; n < 4; ++n) acc[m][n] = zero;

    for (int kt = 0; kt < D_DIM / GBK; ++kt) {
        #pragma unroll
        for (int j = 0; j < 2; ++j) {
            int f = tid + 256 * j;
            int r = f >> 2, kq = f & 3;
            gload_lds16(Abf + (size_t)(row0 + r) * D_DIM + kt * GBK + kq * 8,
                        &As[0][0] + f * 8);
        }
        #pragma unroll
        for (int j = 0; j < 2; ++j) {
            int f = tid + 256 * j;
            int r = f >> 2, kq = f & 3;
            gload_lds16(Bbf + (size_t)(col0 + r) * D_DIM + kt * GBK + kq * 8,
                        &Bs[0][0] + f * 8);
        }
        __syncthreads();

        bf16x8 af[4], bfr[4];
        #pragma unroll
        for (int m = 0; m < 4; ++m)
            af[m] = *(const bf16x8*)&As[wr * 64 + m * 16 + cl][kg * 8];
        #pragma unroll
        for (int n = 0; n < 4; ++n)
            bfr[n] = *(const bf16x8*)&Bs[wc * 64 + n * 16 + cl][kg * 8];

        #pragma unroll
        for (int m = 0; m < 4; ++m)
            #pragma unroll
            for (int n = 0; n < 4; ++n)
                acc[m][n] = __builtin_amdgcn_mfma_f32_16x16x32_bf16(
                    af[m], bfr[n], acc[m][n], 0, 0, 0);
        __syncthreads();
    }

    // epilogue: dist = (xnorm - 2*dot) + cnorm; per-(row,64col) min
    float cn[4];
    #pragma unroll
    for (int n = 0; n < 4; ++n) cn[n] = cnorm[col0 + wc * 64 + n * 16 + cl];
    const int bcol = blockIdx.y * 2 + wc;

    #pragma unroll
    for (int m = 0; m < 4; ++m) {
        const int rbase = row0 + wr * 64 + m * 16 + kg * 4;
        float4 xn4 = *(const float4*)&xnorm[rbase];
        float xn[4] = {xn4.x, xn4.y, xn4.z, xn4.w};
        float rmin[4] = {3.4e38f, 3.4e38f, 3.4e38f, 3.4e38f};
        #pragma unroll
        for (int n = 0; n < 4; ++n) {
            const int col = col0 + wc * 64 + n * 16 + cl;
            f32x4 a = acc[m][n];
            #pragma unroll
            for (int i = 0; i < 4; ++i) {
                float d = (xn[i] - 2.f * a[i]) + cn[n];
                dist[(size_t)(rbase + i) * K_CENT + col] = d;
                rmin[i] = fminf(rmin[i], d);
            }
        }
        #pragma unroll
        for (int i = 0; i < 4; ++i) {
            #pragma unroll
            for (int off = 8; off >= 1; off >>= 1)
                rmin[i] = fminf(rmin[i], __shfl_xor(rmin[i], off));
        }
        if (cl == 0) {
            #pragma unroll
            for (int i = 0; i < 4; ++i)
                blockmins[(size_t)(rbase + i) * 256 + bcol] = rmin[i];
        }
    }
}

// -------- recheck v2: candidate COLUMNS via coalesced dist re-read ---------
// One wave per row; 4 rows per 256-thread block.
__global__ __launch_bounds__(256)
void recheck_finalize(const float* __restrict__ feat,
                      const float* __restrict__ cent,
                      const float* __restrict__ xnorm,
                      const float* __restrict__ cnorm,
                      const float* __restrict__ blockmins,
                      const float* __restrict__ dist,
                      float* __restrict__ quant,
                      float* __restrict__ ids) {
    __shared__ float bms[4][256];
    const int tid = threadIdx.x;
    const int wv = tid >> 6;
    const int lane = tid & 63;
    const int row = blockIdx.x * 4 + wv;

    // per-lane x fragment (float4, lane*4..lane*4+3) held in registers
    float4 xv = ((const float4*)(feat + (size_t)row * D_DIM))[lane];
    float4 bm4 = ((const float4*)(blockmins + (size_t)row * 256))[lane];
    ((float4*)&bms[wv][0])[lane] = bm4;   // wave-private LDS region, no barrier

    // exact row min of the bf16-based dists (min over 256 block mins)
    float gmin = fminf(fminf(bm4.x, bm4.y), fminf(bm4.z, bm4.w));
    #pragma unroll
    for (int off = 32; off >= 1; off >>= 1)
        gmin = fminf(gmin, __shfl_xor(gmin, off));

    // worst-case |bf16dist - exactdist| <= ~0.13 ; 1.0 gives 7x margin
    const float thr = gmin + 1.0f;
    const float xn = xnorm[row];
    const float* drow = dist + (size_t)row * K_CENT;

    unsigned long long best = 0xFFFFFFFFFFFFFFFFull;
    for (int b = 0; b < 256; ++b) {
        if (bms[wv][b] <= thr) {                 // wave-uniform branch
            float d = drow[b * 64 + lane];       // coalesced 256B
            unsigned long long m = __ballot(d <= thr);
            while (m) {                          // wave-uniform candidate loop
                int l = __ffsll((unsigned long long)m) - 1;
                m &= m - 1;
                int c = b * 64 + l;
                // wave-cooperative exact f32 distance for center c
                float4 cv = ((const float4*)(cent + (size_t)c * D_DIM))[lane];
                float p = fmaf(xv.x, cv.x,
                          fmaf(xv.y, cv.y,
                          fmaf(xv.z, cv.z, xv.w * cv.w)));
                #pragma unroll
                for (int off = 32; off >= 1; off >>= 1)
                    p += __shfl_xor(p, off);     // pairwise tree sum
                float dd = (xn - 2.f * p) + cnorm[c];
                unsigned long long key =
                    ((unsigned long long)fkey(dd) << 32) | (unsigned)c;
                best = (key < best) ? key : best;
            }
        }
    }
    // best is wave-uniform (reduced p identical on all lanes)
    const unsigned bidx = (unsigned)(best & 0xFFFFFFFFu);
    if (lane == 0) ids[row] = (float)bidx;
    float4 v = ((const float4*)(cent + (size_t)bidx * D_DIM))[lane];
    ((float4*)(quant + (size_t)row * D_DIM))[lane] = v;
}

// ============================ launch ============================
extern "C" void kernel_launch(void* const* d_in, const int* in_sizes, int n_in,
                              void* d_out, int out_size, void* d_ws, size_t ws_size,
                              hipStream_t stream) {
    const float* feat = (const float*)d_in[0];   // 8192 x 256
    const float* cent = (const float*)d_in[1];   // 16384 x 256

    float* out = (float*)d_out;
    float* quant = out;                 // 2097152
    float* ids   = out + 2097152;       // 8192
    float* dist  = out + 2105344;       // 8192*16384

    char* ws = (char*)d_ws;
    unsigned short* Abf = (unsigned short*)ws;                       // 4MB
    unsigned short* Bbf = (unsigned short*)(ws + (4u << 20));        // 8MB
    float* blockmins    = (float*)(ws + (12u << 20));                // 8MB
    float* xnorm        = (float*)(ws + (20u << 20));                // 32KB
    float* cnorm        = xnorm + N_ROWS;                            // 64KB

    // prep: convert + norms, one wave/row, 4 waves/block
    {
        int waves = N_ROWS + K_CENT;
        prep_kernel<<<(waves * 64 + 255) / 256, 256, 0, stream>>>(
            feat, cent, Abf, Bbf, xnorm, cnorm);
    }

    // dist GEMM (bf16 MFMA) + per-64col block mins
    dist_mfma<<<dim3(N_ROWS / GBM, K_CENT / GBN), 256, 0, stream>>>(
        Abf, Bbf, xnorm, cnorm, dist, blockmins);

    // exact argmin recheck (candidate columns only) + finalize
    recheck_finalize<<<N_ROWS / 4, 256, 0, stream>>>(
        feat, cent, xnorm, cnorm, blockmins, dist, quant, ids);
}